// Round 9
// baseline (273.861 us; speedup 1.0000x reference)
//
#include <hip/hip_runtime.h>
#include <hip/hip_bf16.h>

#define NN 8192
#define DD 128
#define DQK 256
#define EE 262144
#define EDGE_DIM 50
#define HID 32
#define CAP 96                               // per-row edge cap (Poisson(32))
#define SCALE 0.08838834764831845f          // 1/sqrt(128)
#define SCALE_LOG2E 0.12752455522410585f    // SCALE * log2(e)

using f32x4 = __attribute__((ext_vector_type(4))) float;
using f32x2 = __attribute__((ext_vector_type(2))) float;
using bf16x8 = __attribute__((ext_vector_type(8))) short;  // 8 bf16 = 4 VGPRs
using s16x4 = __attribute__((ext_vector_type(4))) short;

static __device__ __forceinline__ short f2b(float f) {
  __hip_bfloat16 h = __float2bfloat16(f);
  return __builtin_bit_cast(short, h);
}
static __device__ __forceinline__ float b2f(short s) {
  unsigned u = ((unsigned)(unsigned short)s) << 16;
  return __builtin_bit_cast(float, u);
}
// async global->LDS, 16B per lane; lds dest = wave-uniform base + lane*16
static __device__ __forceinline__ void gll(const short* g, short* l) {
  __builtin_amdgcn_global_load_lds(
      (const __attribute__((address_space(1))) void*)g,
      (__attribute__((address_space(3))) void*)l, 16, 0, 0);
}

// ---------------- K1: heterogeneous prep + MLP, one dispatch (R3, frozen) ----
// blocks [0,4096):    qkb[n][0:128]=mag*cos, [128:256]=mag*sin; vb16=[mag|ph]
// blocks [4096,4608): vtb[f][n] transpose via 64x64 LDS tiles
// blocks [4608,5632): edge MLP, scalar-broadcast weights.
__global__ __launch_bounds__(256) void k1_mega(
    const float* __restrict__ mag, const float* __restrict__ phase,
    short* __restrict__ qkb, short* __restrict__ vtb, short* __restrict__ vb16,
    const float* __restrict__ rbf, const float* __restrict__ W1,
    const float* __restrict__ b1, const float* __restrict__ W2,
    const float* __restrict__ b2, const int* __restrict__ eidx,
    float* __restrict__ bias, int* __restrict__ cnt, int* __restrict__ slot) {
  __shared__ float tile[64][65];
  int b = blockIdx.x;
  int tid = threadIdx.x;
  if (b < 4096) {
    int t = b * 256 + tid;
    int n = t >> 7, d = t & 127;
    float m = mag[t], p = phase[t];
    float sn, cs;
    __sincosf(p, &sn, &cs);
    qkb[(size_t)n * DQK + d] = f2b(m * cs);
    qkb[(size_t)n * DQK + 128 + d] = f2b(m * sn);
    vb16[(size_t)n * DQK + d] = f2b(m);
    vb16[(size_t)n * DQK + 128 + d] = f2b(p);
    return;
  }
  if (b < 4608) {
    int r = b - 4096;
    int bn = r & 127, bd = (r >> 7) & 1, sel = r >> 8;
    const float* src = sel ? phase : mag;
#pragma unroll
    for (int rep = 0; rep < 16; ++rep) {
      int idx = rep * 256 + tid;
      int rr = idx >> 6, c = idx & 63;
      tile[rr][c] = src[(size_t)(bn * 64 + rr) * DD + bd * 64 + c];
    }
    __syncthreads();
#pragma unroll
    for (int rep = 0; rep < 16; ++rep) {
      int idx = rep * 256 + tid;
      int rr = idx >> 6, c = idx & 63;
      vtb[(size_t)(sel * 128 + bd * 64 + rr) * NN + bn * 64 + c] = f2b(tile[c][rr]);
    }
    return;
  }
  // ---- MLP branch (1 edge/thread, scalar-broadcast weights) ----
  int e = (b - 4608) * 256 + tid;
  const float* rrow = rbf + (size_t)e * EDGE_DIM;
  f32x4 r4[12];
#pragma unroll
  for (int k = 0; k < 12; ++k) r4[k] = *reinterpret_cast<const f32x4*>(rrow + 4 * k);
  f32x2 rt2 = *reinterpret_cast<const f32x2*>(rrow + 48);
  float h[HID];
#pragma unroll
  for (int jj = 0; jj < HID; ++jj) h[jj] = b1[jj];  // uniform -> s_load
#pragma unroll
  for (int k = 0; k < 48; ++k) {
    float r = r4[k >> 2][k & 3];
#pragma unroll
    for (int jj = 0; jj < HID; ++jj) h[jj] += r * W1[k * HID + jj];  // s_load
  }
#pragma unroll
  for (int jj = 0; jj < HID; ++jj)
    h[jj] += rt2.x * W1[48 * HID + jj] + rt2.y * W1[49 * HID + jj];
  float outv = b2[0];
#pragma unroll
  for (int jj = 0; jj < HID; ++jj) {
    float x = h[jj];
    outv += W2[jj] * (x / (1.0f + __expf(-x)));
  }
  bias[e] = outv;
  int i = eidx[e];
  int p = atomicAdd(&cnt[i], 1);
  if (p < CAP) slot[i * CAP + p] = e;
}

// ---------------- K2: per-row duplicate merge -> (j, exp(sum b)) list --------
// R21: moves old-k6's merge up front. For each row: first occurrence of a
// duplicate (i,j) keeps exp(sum of biases), others get eb=1.0 (no-op marker).
// Output feeds k5's in-LDS P correction; k6 shrinks to pure normalize.
__global__ __launch_bounds__(64) void k2_merge(
    const int* __restrict__ eidx, const float* __restrict__ bias,
    const int* __restrict__ cntArr, const int* __restrict__ slot,
    int2* __restrict__ edgeJB, int* __restrict__ mcnt) {
  __shared__ int js[CAP];
  __shared__ float bs[CAP];
  int i = blockIdx.x;
  int lane = threadIdx.x;
  int cnt = cntArr[i];
  if (cnt > CAP) cnt = CAP;
  for (int p = lane; p < cnt; p += 64) {
    int e = slot[i * CAP + p];
    js[p] = eidx[EE + e];
    bs[p] = bias[e];
  }
  __syncthreads();
  for (int p = lane; p < cnt; p += 64) {
    int j = js[p];
    float bsum = bs[p];
    int keep = 1;
    for (int qq = 0; qq < cnt; ++qq) {
      if (qq == p || js[qq] != j) continue;
      if (qq < p) { keep = 0; break; }
      bsum += bs[qq];
    }
    int2 v;
    v.x = j;
    v.y = __float_as_int(keep ? __expf(bsum) : 1.0f);
    edgeJB[(size_t)i * CAP + p] = v;
  }
  if (lane == 0) mcnt[i] = cnt;
}

// ---------------- K5: fused dense flash + in-LDS sparse bias (R21) -----------
// R15 base (frozen structure: S^T + packed Ps, 2 blk/CU at exactly 80K LDS).
// R21 adds a per-chunk RMW phase: 8 threads/row scan the row's merged edge
// list; for j in [c0,c0+128): Ps[row][j-c0] *= eb (bf16), den correction
// oldp*(eb-1) accumulates in a per-thread register (NO extra LDS -> keeps
// 2 blk/CU). Replaces k6's 270MB of scattered K/V re-gathers entirely.
constexpr int TBM = 64;
constexpr int TBN = 128;

template <int NSPLIT>
__global__ __launch_bounds__(512, 4) void k5_flash(
    const short* __restrict__ qk,  // [N][256] bf16
    const short* __restrict__ vt,  // [256][N] bf16
    const int2* __restrict__ ejb,  // [N][CAP] merged (j, eb)
    const int* __restrict__ mcnt,  // [N]
    float* __restrict__ nump,      // [NSPLIT][N][256]
    float* __restrict__ denp) {    // [NSPLIT][N]
  constexpr int QCOLS = NN / NSPLIT;
  constexpr int NCHUNK = QCOLS / TBN;
  constexpr int GPQ = 8 / NSPLIT;
  __shared__ alignas(16) short Qs[TBM * 256];     // 32 KiB, swizzled
  __shared__ alignas(16) short KV[2 * TBN * 64];  // 32 KiB: K dbuf / V subtile
  __shared__ alignas(16) short Ps[TBM * 128];     // 16 KiB, swizzled
  int b = blockIdx.x;
  int q = (b & 7) / GPQ;
  int rb = (b >> 3) * GPQ + (b & (GPQ - 1));
  int tid = threadIdx.x;
  int w = tid >> 6, lane = tid & 63;
  int wr = w >> 2, wc = w & 3;
  int l15 = lane & 15, quad = lane >> 4;
  int rsw = l15 & 7;  // read-side swizzle key (row&7 == l15&7 for all frags)
  int wbase = w * 64; // lane-linear staging base per wave
  int r0 = rb * TBM;
  int cbase = q * QCOLS;
  // RMW assignment: 8 threads per row
  int row8 = tid >> 3, sl0 = tid & 7;
  int mc = mcnt[r0 + row8];
  const int2* erow = ejb + (size_t)(r0 + row8) * CAP;
  float denAcc = 0.f;

  // ---- stage Q tile once: 4 passes x 8KB, direct to LDS ----
#pragma unroll
  for (int p = 0; p < 4; ++p) {
    int idx = p * 512 + tid;
    int row = idx >> 5, gs = idx & 31;
    gll(qk + (size_t)(r0 + row) * DQK + ((gs ^ (row & 7)) * 8),
        &Qs[(p * 512 + wbase) * 8]);
  }

  f32x4 o[2][4] = {};
  float den[2] = {0.f, 0.f};
  __syncthreads();

  for (int ch = 0; ch < NCHUNK; ++ch) {
    int c0 = cbase + ch * TBN;
    // ---- stage K slice bk=0 into buf0 ----
#pragma unroll
    for (int p = 0; p < 2; ++p) {
      int idx = p * 512 + tid;
      int col = idx >> 3, gs = idx & 7;
      gll(qk + (size_t)(c0 + col) * DQK + ((gs ^ (col & 7)) * 8),
          &KV[(p * 512 + wbase) * 8]);
    }
    __syncthreads();
    f32x4 s[2][2] = {};  // s[ct][rt] = S^T fragment (swapped operands)
#pragma unroll
    for (int bk = 0; bk < 4; ++bk) {
      int buf = bk & 1;
      if (bk < 3) {
        int nb = buf ^ 1;
#pragma unroll
        for (int p = 0; p < 2; ++p) {
          int idx = p * 512 + tid;
          int col = idx >> 3, gs = idx & 7;
          gll(qk + (size_t)(c0 + col) * DQK + (bk + 1) * 64 + ((gs ^ (col & 7)) * 8),
              &KV[nb * 8192 + (p * 512 + wbase) * 8]);
        }
      }
#pragma unroll
      for (int ks = 0; ks < 2; ++ks) {
        int g = ks * 4 + quad;
        bf16x8 a[2], bb[2];
#pragma unroll
        for (int rt = 0; rt < 2; ++rt)
          a[rt] = *(const bf16x8*)&Qs[(wr * 32 + rt * 16 + l15) * 256 +
                                      ((bk * 8 + g) ^ rsw) * 8];
#pragma unroll
        for (int ct = 0; ct < 2; ++ct)
          bb[ct] = *(const bf16x8*)&KV[buf * 8192 + (wc * 32 + ct * 16 + l15) * 64 +
                                       (g ^ rsw) * 8];
        // swapped: A = K-frag (m = K-col), B = Q-frag (n = Q-row) -> S^T
#pragma unroll
        for (int rt = 0; rt < 2; ++rt)
#pragma unroll
          for (int ct = 0; ct < 2; ++ct)
            s[ct][rt] = __builtin_amdgcn_mfma_f32_16x16x32_bf16(bb[ct], a[rt],
                                                                s[ct][rt], 0, 0, 0);
      }
      __syncthreads();
    }
    // ---- stage V jb=0 early (K dbuf dead); hides V latency under exp ----
#pragma unroll
    for (int p = 0; p < 4; ++p) {
      int idx = p * 512 + tid;
      int feat = idx >> 3, gs = idx & 7;
      gll(vt + (size_t)feat * NN + c0 + ((gs ^ (feat & 7)) * 8),
          &KV[(p * 512 + wbase) * 8]);
    }
    // ---- exp + packed P->LDS (S^T: lane holds 4 consecutive cols/row) ----
#pragma unroll
    for (int rt = 0; rt < 2; ++rt) {
      int row = wr * 32 + rt * 16 + l15;
#pragma unroll
      for (int ct = 0; ct < 2; ++ct) {
        s16x4 pk;
#pragma unroll
        for (int r = 0; r < 4; ++r) {
          float pv = exp2f(s[ct][rt][r] * SCALE_LOG2E);
          den[rt] += pv;
          pk[r] = f2b(pv);
        }
        int cg = wc * 4 + ct * 2 + (quad >> 1);  // col granule = col>>3
        *reinterpret_cast<s16x4*>(
            &Ps[row * 128 + ((cg ^ (row & 7)) * 8 + (quad & 1) * 4)]) = pk;
      }
    }
    __syncthreads();  // drains Ps (lgkm) + V jb=0 (vm)
    // ---- sparse bias RMW: Ps[row][j-c0] *= eb for this chunk's edges ----
    for (int t = sl0; t < mc; t += 8) {
      int2 jb2 = erow[t];
      unsigned dj = (unsigned)(jb2.x - c0);
      if (dj < (unsigned)TBN) {
        float eb = __int_as_float(jb2.y);
        if (eb != 1.0f) {
          short* ps = &Ps[row8 * 128 + (((dj >> 3) ^ (row8 & 7)) * 8 + (int)(dj & 7))];
          float oldp = b2f(*ps);
          *ps = f2b(oldp * eb);
          denAcc += oldp * (eb - 1.0f);
        }
      }
    }
    __syncthreads();  // RMW visible before PV pa reads
    // ---- PV: V subtiles of 64 cols ----
#pragma unroll
    for (int jb = 0; jb < 2; ++jb) {
      if (jb == 1) {
        __syncthreads();  // all jb=0 vb reads done before restage
#pragma unroll
        for (int p = 0; p < 4; ++p) {
          int idx = p * 512 + tid;
          int feat = idx >> 3, gs = idx & 7;
          gll(vt + (size_t)feat * NN + c0 + 64 + ((gs ^ (feat & 7)) * 8),
              &KV[(p * 512 + wbase) * 8]);
        }
        __syncthreads();
      }
#pragma unroll
      for (int ks = 0; ks < 2; ++ks) {
        int g = ks * 4 + quad;
        bf16x8 pa[2], vb[4];
#pragma unroll
        for (int rt = 0; rt < 2; ++rt) {
          int row = wr * 32 + rt * 16 + l15;
          pa[rt] = *(const bf16x8*)&Ps[row * 128 +
                                       (((jb * 8 + g) ^ (row & 7)) * 8)];
        }
#pragma unroll
        for (int ft = 0; ft < 4; ++ft)
          vb[ft] = *(const bf16x8*)&KV[(wc * 64 + ft * 16 + l15) * 64 + (g ^ rsw) * 8];
#pragma unroll
        for (int rt = 0; rt < 2; ++rt)
#pragma unroll
          for (int ft = 0; ft < 4; ++ft)
            o[rt][ft] = __builtin_amdgcn_mfma_f32_16x16x32_bf16(pa[rt], vb[ft],
                                                                o[rt][ft], 0, 0, 0);
      }
    }
    __syncthreads();  // protect Ps/KV rewrite next chunk
  }
  // ---- epilogue: write partial num ----
  float* npB = nump + (size_t)q * NN * DQK;
#pragma unroll
  for (int rt = 0; rt < 2; ++rt)
#pragma unroll
    for (int ft = 0; ft < 4; ++ft) {
      int row = r0 + wr * 32 + rt * 16 + quad * 4;
      int feat = wc * 64 + ft * 16 + l15;
#pragma unroll
      for (int r = 0; r < 4; ++r)
        npB[(size_t)(row + r) * DQK + feat] = o[rt][ft][r];
    }
  // ---- den: dense part reduce (quads, wc) + sparse corr (8-lane groups) ----
  float* dl = reinterpret_cast<float*>(KV);        // [4][TBM], KV dead here
  float* corr = reinterpret_cast<float*>(KV) + 4 * TBM;  // [TBM]
#pragma unroll
  for (int rt = 0; rt < 2; ++rt) {
    float d = den[rt];
    d += __shfl_xor(d, 16);
    d += __shfl_xor(d, 32);
    if (lane < 16) dl[wc * TBM + wr * 32 + rt * 16 + lane] = d;
  }
  denAcc += __shfl_xor(denAcc, 1);
  denAcc += __shfl_xor(denAcc, 2);
  denAcc += __shfl_xor(denAcc, 4);
  if (sl0 == 0) corr[row8] = denAcc;
  __syncthreads();
  if (tid < TBM) {
    float d = dl[0 * TBM + tid] + dl[1 * TBM + tid] + dl[2 * TBM + tid] +
              dl[3 * TBM + tid] + corr[tid];
    denp[q * NN + r0 + tid] = d;
  }
}

// ---------------- K6: pure normalize (bias already folded into k5) -----------
__global__ __launch_bounds__(64) void k6_norm(
    const float* __restrict__ nump, const float* __restrict__ denp,
    float* __restrict__ out, int nsplit) {
  int i = blockIdx.x;
  int lane = threadIdx.x;
  f32x4 a = {0.f, 0.f, 0.f, 0.f};
  float den = 0.f;
  for (int qq = 0; qq < nsplit; ++qq) {
    a += *reinterpret_cast<const f32x4*>(nump + ((size_t)qq * NN + i) * DQK + lane * 4);
    den += denp[qq * NN + i];
  }
  float inv = 1.0f / den;
  a *= inv;
  // feats f = lane*4..+3; f<128 -> new_mag, else new_phase (no 128-crossing)
  float* dst = (lane < 32) ? (out + (size_t)i * DD + lane * 4)
                           : (out + (size_t)NN * DD + (size_t)i * DD + lane * 4 - 128);
  *reinterpret_cast<f32x4*>(dst) = a;
}

// ---------------- workspace layout -------------------------------------------
constexpr size_t OFF_QK = 0;                                   // 4 MiB bf16
constexpr size_t OFF_VT = (size_t)NN * DQK * 2;                // 4 MiB bf16
constexpr size_t OFF_VB16 = OFF_VT + (size_t)DQK * NN * 2;     // 4 MiB bf16
constexpr size_t OFF_BIAS = OFF_VB16 + (size_t)NN * DQK * 2;   // 1 MiB f32
constexpr size_t OFF_CNT = OFF_BIAS + (size_t)EE * 4;
constexpr size_t OFF_SLOT = OFF_CNT + (size_t)NN * 4;
constexpr size_t OFF_EJB = (OFF_SLOT + (size_t)NN * CAP * 4 + 255) & ~(size_t)255;
constexpr size_t OFF_MCNT = OFF_EJB + (size_t)NN * CAP * 8;
constexpr size_t OFF_NUMP = (OFF_MCNT + (size_t)NN * 4 + 255) & ~(size_t)255;
constexpr size_t WS_NEED4 = OFF_NUMP + 4ull * NN * DQK * 4 + 4ull * NN * 4;
constexpr size_t WS_NEED2 = OFF_NUMP + 2ull * NN * DQK * 4 + 2ull * NN * 4;

extern "C" void kernel_launch(void* const* d_in, const int* in_sizes, int n_in,
                              void* d_out, int out_size, void* d_ws, size_t ws_size,
                              hipStream_t stream) {
  const float* mag = (const float*)d_in[0];
  const float* phase = (const float*)d_in[1];
  const int* eidx = (const int*)d_in[2];
  const float* rbf = (const float*)d_in[3];
  const float* W1 = (const float*)d_in[4];
  const float* b1 = (const float*)d_in[5];
  const float* W2 = (const float*)d_in[6];
  const float* b2 = (const float*)d_in[7];
  float* out = (float*)d_out;
  char* ws = (char*)d_ws;
  if (ws_size < WS_NEED2) return;
  int nsplit = (ws_size >= WS_NEED4) ? 4 : 2;

  short* qkb = (short*)(ws + OFF_QK);
  short* vtb = (short*)(ws + OFF_VT);
  short* vb16 = (short*)(ws + OFF_VB16);
  float* bias = (float*)(ws + OFF_BIAS);
  int* cnt = (int*)(ws + OFF_CNT);
  int* slot = (int*)(ws + OFF_SLOT);
  int2* edgeJB = (int2*)(ws + OFF_EJB);
  int* mcnt = (int*)(ws + OFF_MCNT);
  float* nump = (float*)(ws + OFF_NUMP);
  float* denp = (float*)(ws + OFF_NUMP + (size_t)nsplit * NN * DQK * 4);

  hipMemsetAsync(cnt, 0, (size_t)NN * 4, stream);
  k1_mega<<<5632, 256, 0, stream>>>(mag, phase, qkb, vtb, vb16, rbf, W1, b1, W2,
                                    b2, eidx, bias, cnt, slot);
  k2_merge<<<NN, 64, 0, stream>>>(eidx, bias, cnt, slot, edgeJB, mcnt);
  if (nsplit == 4)
    k5_flash<4><<<(NN / TBM) * 4, 512, 0, stream>>>(qkb, vtb, edgeJB, mcnt, nump, denp);
  else
    k5_flash<2><<<(NN / TBM) * 2, 512, 0, stream>>>(qkb, vtb, edgeJB, mcnt, nump, denp);
  k6_norm<<<NN, 64, 0, stream>>>(nump, denp, out, nsplit);
}

// Round 10
// 266.537 us; speedup vs baseline: 1.0275x; 1.0275x over previous
//
#include <hip/hip_runtime.h>
#include <hip/hip_bf16.h>

#define NN 8192
#define DD 128
#define DQK 256
#define EE 262144
#define EDGE_DIM 50
#define HID 32
#define CAP 96                               // per-row edge cap (Poisson(32))
#define SCALE 0.08838834764831845f          // 1/sqrt(128)
#define SCALE_LOG2E 0.12752455522410585f    // SCALE * log2(e)

using f32x4 = __attribute__((ext_vector_type(4))) float;
using f32x2 = __attribute__((ext_vector_type(2))) float;
using bf16x8 = __attribute__((ext_vector_type(8))) short;  // 8 bf16 = 4 VGPRs
using s16x4 = __attribute__((ext_vector_type(4))) short;

static __device__ __forceinline__ short f2b(float f) {
  __hip_bfloat16 h = __float2bfloat16(f);
  return __builtin_bit_cast(short, h);
}
static __device__ __forceinline__ float b2f(short s) {
  unsigned u = ((unsigned)(unsigned short)s) << 16;
  return __builtin_bit_cast(float, u);
}
// async global->LDS, 16B per lane; lds dest = wave-uniform base + lane*16
static __device__ __forceinline__ void gll(const short* g, short* l) {
  __builtin_amdgcn_global_load_lds(
      (const __attribute__((address_space(1))) void*)g,
      (__attribute__((address_space(3))) void*)l, 16, 0, 0);
}

// ---------------- K1: heterogeneous prep + MLP, one dispatch (R3, frozen) ----
// blocks [0,4096):    qkb[n][0:128]=mag*cos, [128:256]=mag*sin; vb16=[mag|ph]
// blocks [4096,4608): vtb[f][n] transpose via 64x64 LDS tiles
// blocks [4608,5632): edge MLP, scalar-broadcast weights.
__global__ __launch_bounds__(256) void k1_mega(
    const float* __restrict__ mag, const float* __restrict__ phase,
    short* __restrict__ qkb, short* __restrict__ vtb, short* __restrict__ vb16,
    const float* __restrict__ rbf, const float* __restrict__ W1,
    const float* __restrict__ b1, const float* __restrict__ W2,
    const float* __restrict__ b2, const int* __restrict__ eidx,
    float* __restrict__ bias, int* __restrict__ cnt, int* __restrict__ slot) {
  __shared__ float tile[64][65];
  int b = blockIdx.x;
  int tid = threadIdx.x;
  if (b < 4096) {
    int t = b * 256 + tid;
    int n = t >> 7, d = t & 127;
    float m = mag[t], p = phase[t];
    float sn, cs;
    __sincosf(p, &sn, &cs);
    qkb[(size_t)n * DQK + d] = f2b(m * cs);
    qkb[(size_t)n * DQK + 128 + d] = f2b(m * sn);
    vb16[(size_t)n * DQK + d] = f2b(m);
    vb16[(size_t)n * DQK + 128 + d] = f2b(p);
    return;
  }
  if (b < 4608) {
    int r = b - 4096;
    int bn = r & 127, bd = (r >> 7) & 1, sel = r >> 8;
    const float* src = sel ? phase : mag;
#pragma unroll
    for (int rep = 0; rep < 16; ++rep) {
      int idx = rep * 256 + tid;
      int rr = idx >> 6, c = idx & 63;
      tile[rr][c] = src[(size_t)(bn * 64 + rr) * DD + bd * 64 + c];
    }
    __syncthreads();
#pragma unroll
    for (int rep = 0; rep < 16; ++rep) {
      int idx = rep * 256 + tid;
      int rr = idx >> 6, c = idx & 63;
      vtb[(size_t)(sel * 128 + bd * 64 + rr) * NN + bn * 64 + c] = f2b(tile[c][rr]);
    }
    return;
  }
  // ---- MLP branch (1 edge/thread, scalar-broadcast weights) ----
  int e = (b - 4608) * 256 + tid;
  const float* rrow = rbf + (size_t)e * EDGE_DIM;
  f32x4 r4[12];
#pragma unroll
  for (int k = 0; k < 12; ++k) r4[k] = *reinterpret_cast<const f32x4*>(rrow + 4 * k);
  f32x2 rt2 = *reinterpret_cast<const f32x2*>(rrow + 48);
  float h[HID];
#pragma unroll
  for (int jj = 0; jj < HID; ++jj) h[jj] = b1[jj];  // uniform -> s_load
#pragma unroll
  for (int k = 0; k < 48; ++k) {
    float r = r4[k >> 2][k & 3];
#pragma unroll
    for (int jj = 0; jj < HID; ++jj) h[jj] += r * W1[k * HID + jj];  // s_load
  }
#pragma unroll
  for (int jj = 0; jj < HID; ++jj)
    h[jj] += rt2.x * W1[48 * HID + jj] + rt2.y * W1[49 * HID + jj];
  float outv = b2[0];
#pragma unroll
  for (int jj = 0; jj < HID; ++jj) {
    float x = h[jj];
    outv += W2[jj] * (x / (1.0f + __expf(-x)));
  }
  bias[e] = outv;
  int i = eidx[e];
  int p = atomicAdd(&cnt[i], 1);
  if (p < CAP) slot[i * CAP + p] = e;
}

// ---------------- K2: per-row merge -> packed (j<<16 | bf16(exp(sum b))) -----
// First occurrence of duplicate (i,j) keeps exp(sum of biases); dups and
// empty slots get sentinel 0xFFFF0000 (j=65535, never matches a chunk).
// Packed u32 (j:13 bits hi, eb:bf16 lo) so k5 can hold its slice in 12 VGPRs.
__global__ __launch_bounds__(64) void k2_merge(
    const int* __restrict__ eidx, const float* __restrict__ bias,
    const int* __restrict__ cntArr, const int* __restrict__ slot,
    unsigned* __restrict__ edgeJB, int* __restrict__ mcnt) {
  __shared__ int js[CAP];
  __shared__ float bs[CAP];
  int i = blockIdx.x;
  int lane = threadIdx.x;
  int cnt = cntArr[i];
  if (cnt > CAP) cnt = CAP;
  for (int p = lane; p < cnt; p += 64) {
    int e = slot[i * CAP + p];
    js[p] = eidx[EE + e];
    bs[p] = bias[e];
  }
  __syncthreads();
  for (int p = lane; p < cnt; p += 64) {
    int j = js[p];
    float bsum = bs[p];
    int keep = 1;
    for (int qq = 0; qq < cnt; ++qq) {
      if (qq == p || js[qq] != j) continue;
      if (qq < p) { keep = 0; break; }
      bsum += bs[qq];
    }
    unsigned v = keep ? (((unsigned)j << 16) |
                         (unsigned short)f2b(__expf(bsum)))
                      : 0xFFFF0000u;
    edgeJB[(size_t)i * CAP + p] = v;
  }
  if (lane == 0) mcnt[i] = cnt;
}

// ---------------- K5: fused dense flash + reg-resident sparse bias (R22) -----
// R21 lesson: per-chunk GLOBAL re-reads of the edge list cost +31.7us (FETCH
// 14->22MB, dependent-load latency at 4 waves/SIMD). R22: each of the 8
// threads/row preloads its list slice ONCE into 12 packed u32 registers
// (static-indexed unroll; 64+12+48acc = 124 <= 128 unified budget, no spill).
// Per-chunk scan = 12 unrolled VALU compares + rare LDS RMW. Same math as R21.
constexpr int TBM = 64;
constexpr int TBN = 128;

template <int NSPLIT>
__global__ __launch_bounds__(512, 4) void k5_flash(
    const short* __restrict__ qk,      // [N][256] bf16
    const short* __restrict__ vt,      // [256][N] bf16
    const unsigned* __restrict__ ejb,  // [N][CAP] packed (j<<16 | bf16 eb)
    const int* __restrict__ mcnt,      // [N]
    float* __restrict__ nump,          // [NSPLIT][N][256]
    float* __restrict__ denp) {        // [NSPLIT][N]
  constexpr int QCOLS = NN / NSPLIT;
  constexpr int NCHUNK = QCOLS / TBN;
  constexpr int GPQ = 8 / NSPLIT;
  __shared__ alignas(16) short Qs[TBM * 256];     // 32 KiB, swizzled
  __shared__ alignas(16) short KV[2 * TBN * 64];  // 32 KiB: K dbuf / V subtile
  __shared__ alignas(16) short Ps[TBM * 128];     // 16 KiB, swizzled
  int b = blockIdx.x;
  int q = (b & 7) / GPQ;
  int rb = (b >> 3) * GPQ + (b & (GPQ - 1));
  int tid = threadIdx.x;
  int w = tid >> 6, lane = tid & 63;
  int wr = w >> 2, wc = w & 3;
  int l15 = lane & 15, quad = lane >> 4;
  int rsw = l15 & 7;  // read-side swizzle key (row&7 == l15&7 for all frags)
  int wbase = w * 64; // lane-linear staging base per wave
  int r0 = rb * TBM;
  int cbase = q * QCOLS;

  // ---- stage Q tile once: 4 passes x 8KB, direct to LDS ----
#pragma unroll
  for (int p = 0; p < 4; ++p) {
    int idx = p * 512 + tid;
    int row = idx >> 5, gs = idx & 31;
    gll(qk + (size_t)(r0 + row) * DQK + ((gs ^ (row & 7)) * 8),
        &Qs[(p * 512 + wbase) * 8]);
  }

  // ---- preload this thread's edge-list slice into registers (once) ----
  int row8 = tid >> 3, sl0 = tid & 7;  // 8 threads per row
  int mc = mcnt[r0 + row8];
  const unsigned* erow = ejb + (size_t)(r0 + row8) * CAP;
  unsigned myE[12];  // CAP/8 = 12, all indices static (rule #20)
#pragma unroll
  for (int u = 0; u < 12; ++u) {
    int t = sl0 + u * 8;
    myE[u] = (t < mc) ? erow[t] : 0xFFFF0000u;
  }
  float denAcc = 0.f;

  f32x4 o[2][4] = {};
  float den[2] = {0.f, 0.f};
  __syncthreads();

  for (int ch = 0; ch < NCHUNK; ++ch) {
    int c0 = cbase + ch * TBN;
    // ---- stage K slice bk=0 into buf0 ----
#pragma unroll
    for (int p = 0; p < 2; ++p) {
      int idx = p * 512 + tid;
      int col = idx >> 3, gs = idx & 7;
      gll(qk + (size_t)(c0 + col) * DQK + ((gs ^ (col & 7)) * 8),
          &KV[(p * 512 + wbase) * 8]);
    }
    __syncthreads();
    f32x4 s[2][2] = {};  // s[ct][rt] = S^T fragment (swapped operands)
#pragma unroll
    for (int bk = 0; bk < 4; ++bk) {
      int buf = bk & 1;
      if (bk < 3) {
        int nb = buf ^ 1;
#pragma unroll
        for (int p = 0; p < 2; ++p) {
          int idx = p * 512 + tid;
          int col = idx >> 3, gs = idx & 7;
          gll(qk + (size_t)(c0 + col) * DQK + (bk + 1) * 64 + ((gs ^ (col & 7)) * 8),
              &KV[nb * 8192 + (p * 512 + wbase) * 8]);
        }
      }
#pragma unroll
      for (int ks = 0; ks < 2; ++ks) {
        int g = ks * 4 + quad;
        bf16x8 a[2], bb[2];
#pragma unroll
        for (int rt = 0; rt < 2; ++rt)
          a[rt] = *(const bf16x8*)&Qs[(wr * 32 + rt * 16 + l15) * 256 +
                                      ((bk * 8 + g) ^ rsw) * 8];
#pragma unroll
        for (int ct = 0; ct < 2; ++ct)
          bb[ct] = *(const bf16x8*)&KV[buf * 8192 + (wc * 32 + ct * 16 + l15) * 64 +
                                       (g ^ rsw) * 8];
        // swapped: A = K-frag (m = K-col), B = Q-frag (n = Q-row) -> S^T
#pragma unroll
        for (int rt = 0; rt < 2; ++rt)
#pragma unroll
          for (int ct = 0; ct < 2; ++ct)
            s[ct][rt] = __builtin_amdgcn_mfma_f32_16x16x32_bf16(bb[ct], a[rt],
                                                                s[ct][rt], 0, 0, 0);
      }
      __syncthreads();
    }
    // ---- stage V jb=0 early (K dbuf dead); hides V latency under exp ----
#pragma unroll
    for (int p = 0; p < 4; ++p) {
      int idx = p * 512 + tid;
      int feat = idx >> 3, gs = idx & 7;
      gll(vt + (size_t)feat * NN + c0 + ((gs ^ (feat & 7)) * 8),
          &KV[(p * 512 + wbase) * 8]);
    }
    // ---- exp + packed P->LDS (S^T: lane holds 4 consecutive cols/row) ----
#pragma unroll
    for (int rt = 0; rt < 2; ++rt) {
      int row = wr * 32 + rt * 16 + l15;
#pragma unroll
      for (int ct = 0; ct < 2; ++ct) {
        s16x4 pk;
#pragma unroll
        for (int r = 0; r < 4; ++r) {
          float pv = exp2f(s[ct][rt][r] * SCALE_LOG2E);
          den[rt] += pv;
          pk[r] = f2b(pv);
        }
        int cg = wc * 4 + ct * 2 + (quad >> 1);  // col granule = col>>3
        *reinterpret_cast<s16x4*>(
            &Ps[row * 128 + ((cg ^ (row & 7)) * 8 + (quad & 1) * 4)]) = pk;
      }
    }
    __syncthreads();  // drains Ps (lgkm) + V jb=0 (vm)
    // ---- sparse bias RMW from registers: Ps[row][j-c0] *= eb ----
#pragma unroll
    for (int u = 0; u < 12; ++u) {
      unsigned dj = (myE[u] >> 16) - (unsigned)c0;
      if (dj < (unsigned)TBN) {
        float eb = b2f((short)(myE[u] & 0xFFFFu));
        if (eb != 1.0f) {
          short* ps = &Ps[row8 * 128 + (((dj >> 3) ^ (row8 & 7)) * 8 + (int)(dj & 7))];
          float oldp = b2f(*ps);
          *ps = f2b(oldp * eb);
          denAcc += oldp * (eb - 1.0f);
        }
      }
    }
    __syncthreads();  // RMW visible before PV pa reads
    // ---- PV: V subtiles of 64 cols ----
#pragma unroll
    for (int jb = 0; jb < 2; ++jb) {
      if (jb == 1) {
        __syncthreads();  // all jb=0 vb reads done before restage
#pragma unroll
        for (int p = 0; p < 4; ++p) {
          int idx = p * 512 + tid;
          int feat = idx >> 3, gs = idx & 7;
          gll(vt + (size_t)feat * NN + c0 + 64 + ((gs ^ (feat & 7)) * 8),
              &KV[(p * 512 + wbase) * 8]);
        }
        __syncthreads();
      }
#pragma unroll
      for (int ks = 0; ks < 2; ++ks) {
        int g = ks * 4 + quad;
        bf16x8 pa[2], vb[4];
#pragma unroll
        for (int rt = 0; rt < 2; ++rt) {
          int row = wr * 32 + rt * 16 + l15;
          pa[rt] = *(const bf16x8*)&Ps[row * 128 +
                                       (((jb * 8 + g) ^ (row & 7)) * 8)];
        }
#pragma unroll
        for (int ft = 0; ft < 4; ++ft)
          vb[ft] = *(const bf16x8*)&KV[(wc * 64 + ft * 16 + l15) * 64 + (g ^ rsw) * 8];
#pragma unroll
        for (int rt = 0; rt < 2; ++rt)
#pragma unroll
          for (int ft = 0; ft < 4; ++ft)
            o[rt][ft] = __builtin_amdgcn_mfma_f32_16x16x32_bf16(pa[rt], vb[ft],
                                                                o[rt][ft], 0, 0, 0);
      }
    }
    __syncthreads();  // protect Ps/KV rewrite next chunk
  }
  // ---- epilogue: write partial num ----
  float* npB = nump + (size_t)q * NN * DQK;
#pragma unroll
  for (int rt = 0; rt < 2; ++rt)
#pragma unroll
    for (int ft = 0; ft < 4; ++ft) {
      int row = r0 + wr * 32 + rt * 16 + quad * 4;
      int feat = wc * 64 + ft * 16 + l15;
#pragma unroll
      for (int r = 0; r < 4; ++r)
        npB[(size_t)(row + r) * DQK + feat] = o[rt][ft][r];
    }
  // ---- den: dense part reduce (quads, wc) + sparse corr (8-lane groups) ----
  float* dl = reinterpret_cast<float*>(KV);        // [4][TBM], KV dead here
  float* corr = reinterpret_cast<float*>(KV) + 4 * TBM;  // [TBM]
#pragma unroll
  for (int rt = 0; rt < 2; ++rt) {
    float d = den[rt];
    d += __shfl_xor(d, 16);
    d += __shfl_xor(d, 32);
    if (lane < 16) dl[wc * TBM + wr * 32 + rt * 16 + lane] = d;
  }
  denAcc += __shfl_xor(denAcc, 1);
  denAcc += __shfl_xor(denAcc, 2);
  denAcc += __shfl_xor(denAcc, 4);
  if (sl0 == 0) corr[row8] = denAcc;
  __syncthreads();
  if (tid < TBM) {
    float d = dl[0 * TBM + tid] + dl[1 * TBM + tid] + dl[2 * TBM + tid] +
              dl[3 * TBM + tid] + corr[tid];
    denp[q * NN + r0 + tid] = d;
  }
}

// ---------------- K6: pure normalize (bias already folded into k5) -----------
__global__ __launch_bounds__(64) void k6_norm(
    const float* __restrict__ nump, const float* __restrict__ denp,
    float* __restrict__ out, int nsplit) {
  int i = blockIdx.x;
  int lane = threadIdx.x;
  f32x4 a = {0.f, 0.f, 0.f, 0.f};
  float den = 0.f;
  for (int qq = 0; qq < nsplit; ++qq) {
    a += *reinterpret_cast<const f32x4*>(nump + ((size_t)qq * NN + i) * DQK + lane * 4);
    den += denp[qq * NN + i];
  }
  float inv = 1.0f / den;
  a *= inv;
  // feats f = lane*4..+3; f<128 -> new_mag, else new_phase (no 128-crossing)
  float* dst = (lane < 32) ? (out + (size_t)i * DD + lane * 4)
                           : (out + (size_t)NN * DD + (size_t)i * DD + lane * 4 - 128);
  *reinterpret_cast<f32x4*>(dst) = a;
}

// ---------------- workspace layout -------------------------------------------
constexpr size_t OFF_QK = 0;                                   // 4 MiB bf16
constexpr size_t OFF_VT = (size_t)NN * DQK * 2;                // 4 MiB bf16
constexpr size_t OFF_VB16 = OFF_VT + (size_t)DQK * NN * 2;     // 4 MiB bf16
constexpr size_t OFF_BIAS = OFF_VB16 + (size_t)NN * DQK * 2;   // 1 MiB f32
constexpr size_t OFF_CNT = OFF_BIAS + (size_t)EE * 4;
constexpr size_t OFF_SLOT = OFF_CNT + (size_t)NN * 4;
constexpr size_t OFF_EJB = (OFF_SLOT + (size_t)NN * CAP * 4 + 255) & ~(size_t)255;
constexpr size_t OFF_MCNT = OFF_EJB + (size_t)NN * CAP * 4;
constexpr size_t OFF_NUMP = (OFF_MCNT + (size_t)NN * 4 + 255) & ~(size_t)255;
constexpr size_t WS_NEED4 = OFF_NUMP + 4ull * NN * DQK * 4 + 4ull * NN * 4;
constexpr size_t WS_NEED2 = OFF_NUMP + 2ull * NN * DQK * 4 + 2ull * NN * 4;

extern "C" void kernel_launch(void* const* d_in, const int* in_sizes, int n_in,
                              void* d_out, int out_size, void* d_ws, size_t ws_size,
                              hipStream_t stream) {
  const float* mag = (const float*)d_in[0];
  const float* phase = (const float*)d_in[1];
  const int* eidx = (const int*)d_in[2];
  const float* rbf = (const float*)d_in[3];
  const float* W1 = (const float*)d_in[4];
  const float* b1 = (const float*)d_in[5];
  const float* W2 = (const float*)d_in[6];
  const float* b2 = (const float*)d_in[7];
  float* out = (float*)d_out;
  char* ws = (char*)d_ws;
  if (ws_size < WS_NEED2) return;
  int nsplit = (ws_size >= WS_NEED4) ? 4 : 2;

  short* qkb = (short*)(ws + OFF_QK);
  short* vtb = (short*)(ws + OFF_VT);
  short* vb16 = (short*)(ws + OFF_VB16);
  float* bias = (float*)(ws + OFF_BIAS);
  int* cnt = (int*)(ws + OFF_CNT);
  int* slot = (int*)(ws + OFF_SLOT);
  unsigned* edgeJB = (unsigned*)(ws + OFF_EJB);
  int* mcnt = (int*)(ws + OFF_MCNT);
  float* nump = (float*)(ws + OFF_NUMP);
  float* denp = (float*)(ws + OFF_NUMP + (size_t)nsplit * NN * DQK * 4);

  hipMemsetAsync(cnt, 0, (size_t)NN * 4, stream);
  k1_mega<<<5632, 256, 0, stream>>>(mag, phase, qkb, vtb, vb16, rbf, W1, b1, W2,
                                    b2, eidx, bias, cnt, slot);
  k2_merge<<<NN, 64, 0, stream>>>(eidx, bias, cnt, slot, edgeJB, mcnt);
  if (nsplit == 4)
    k5_flash<4><<<(NN / TBM) * 4, 512, 0, stream>>>(qkb, vtb, edgeJB, mcnt, nump, denp);
  else
    k5_flash<2><<<(NN / TBM) * 2, 512, 0, stream>>>(qkb, vtb, edgeJB, mcnt, nump, denp);
  k6_norm<<<NN, 64, 0, stream>>>(nump, denp, out, nsplit);
}

// Round 11
// 259.314 us; speedup vs baseline: 1.0561x; 1.0279x over previous
//
#include <hip/hip_runtime.h>
#include <hip/hip_bf16.h>

#define NN 8192
#define DD 128
#define DQK 256
#define EE 262144
#define EDGE_DIM 50
#define HID 32
#define CAP 96                               // per-row edge cap (Poisson(32))
#define SCALE 0.08838834764831845f          // 1/sqrt(128)
#define SCALE_LOG2E 0.12752455522410585f    // SCALE * log2(e)

using f32x4 = __attribute__((ext_vector_type(4))) float;
using f32x2 = __attribute__((ext_vector_type(2))) float;
using bf16x8 = __attribute__((ext_vector_type(8))) short;  // 8 bf16 = 4 VGPRs
using s16x4 = __attribute__((ext_vector_type(4))) short;

static __device__ __forceinline__ short f2b(float f) {
  __hip_bfloat16 h = __float2bfloat16(f);
  return __builtin_bit_cast(short, h);
}
static __device__ __forceinline__ float b2f(short s) {
  unsigned u = ((unsigned)(unsigned short)s) << 16;
  return __builtin_bit_cast(float, u);
}
// async global->LDS, 16B per lane; lds dest = wave-uniform base + lane*16
static __device__ __forceinline__ void gll(const short* g, short* l) {
  __builtin_amdgcn_global_load_lds(
      (const __attribute__((address_space(1))) void*)g,
      (__attribute__((address_space(3))) void*)l, 16, 0, 0);
}

// ---------------- K1: heterogeneous prep + MLP, one dispatch (R3, frozen) ----
__global__ __launch_bounds__(256) void k1_mega(
    const float* __restrict__ mag, const float* __restrict__ phase,
    short* __restrict__ qkb, short* __restrict__ vtb, short* __restrict__ vb16,
    const float* __restrict__ rbf, const float* __restrict__ W1,
    const float* __restrict__ b1, const float* __restrict__ W2,
    const float* __restrict__ b2, const int* __restrict__ eidx,
    float* __restrict__ bias, int* __restrict__ cnt, int* __restrict__ slot) {
  __shared__ float tile[64][65];
  int b = blockIdx.x;
  int tid = threadIdx.x;
  if (b < 4096) {
    int t = b * 256 + tid;
    int n = t >> 7, d = t & 127;
    float m = mag[t], p = phase[t];
    float sn, cs;
    __sincosf(p, &sn, &cs);
    qkb[(size_t)n * DQK + d] = f2b(m * cs);
    qkb[(size_t)n * DQK + 128 + d] = f2b(m * sn);
    vb16[(size_t)n * DQK + d] = f2b(m);
    vb16[(size_t)n * DQK + 128 + d] = f2b(p);
    return;
  }
  if (b < 4608) {
    int r = b - 4096;
    int bn = r & 127, bd = (r >> 7) & 1, sel = r >> 8;
    const float* src = sel ? phase : mag;
#pragma unroll
    for (int rep = 0; rep < 16; ++rep) {
      int idx = rep * 256 + tid;
      int rr = idx >> 6, c = idx & 63;
      tile[rr][c] = src[(size_t)(bn * 64 + rr) * DD + bd * 64 + c];
    }
    __syncthreads();
#pragma unroll
    for (int rep = 0; rep < 16; ++rep) {
      int idx = rep * 256 + tid;
      int rr = idx >> 6, c = idx & 63;
      vtb[(size_t)(sel * 128 + bd * 64 + rr) * NN + bn * 64 + c] = f2b(tile[c][rr]);
    }
    return;
  }
  // ---- MLP branch (1 edge/thread, scalar-broadcast weights) ----
  int e = (b - 4608) * 256 + tid;
  const float* rrow = rbf + (size_t)e * EDGE_DIM;
  f32x4 r4[12];
#pragma unroll
  for (int k = 0; k < 12; ++k) r4[k] = *reinterpret_cast<const f32x4*>(rrow + 4 * k);
  f32x2 rt2 = *reinterpret_cast<const f32x2*>(rrow + 48);
  float h[HID];
#pragma unroll
  for (int jj = 0; jj < HID; ++jj) h[jj] = b1[jj];  // uniform -> s_load
#pragma unroll
  for (int k = 0; k < 48; ++k) {
    float r = r4[k >> 2][k & 3];
#pragma unroll
    for (int jj = 0; jj < HID; ++jj) h[jj] += r * W1[k * HID + jj];  // s_load
  }
#pragma unroll
  for (int jj = 0; jj < HID; ++jj)
    h[jj] += rt2.x * W1[48 * HID + jj] + rt2.y * W1[49 * HID + jj];
  float outv = b2[0];
#pragma unroll
  for (int jj = 0; jj < HID; ++jj) {
    float x = h[jj];
    outv += W2[jj] * (x / (1.0f + __expf(-x)));
  }
  bias[e] = outv;
  int i = eidx[e];
  int p = atomicAdd(&cnt[i], 1);
  if (p < CAP) slot[i * CAP + p] = e;
}

// ---------------- K2: merge + SORT by j + prefix offsets (R23) ---------------
// Per row: duplicates merged (summed bias), kept entries sorted ascending by
// j (distinct after merge) and compacted into edgeJB[i][0..kcnt). qoff[i][k] =
// #{kept: j < k*2048}, k=0..4, so k5's cursor can jump to its q-window.
// Packed u32: j<<16 | bf16(exp(sum b)).
__global__ __launch_bounds__(64) void k2_merge(
    const int* __restrict__ eidx, const float* __restrict__ bias,
    const int* __restrict__ cntArr, const int* __restrict__ slot,
    unsigned* __restrict__ edgeJB, int* __restrict__ qoff) {
  __shared__ int js[CAP];
  __shared__ float bsv[CAP];
  __shared__ float bsum_s[CAP];
  __shared__ unsigned char keepf[CAP];
  int i = blockIdx.x;
  int lane = threadIdx.x;
  int cnt = cntArr[i];
  if (cnt > CAP) cnt = CAP;
  for (int p = lane; p < cnt; p += 64) {
    int e = slot[i * CAP + p];
    js[p] = eidx[EE + e];
    bsv[p] = bias[e];
  }
  __syncthreads();
  for (int p = lane; p < cnt; p += 64) {
    int j = js[p];
    float bsum = bsv[p];
    int kp = 1;
    for (int qq = 0; qq < cnt; ++qq) {
      if (qq == p || js[qq] != j) continue;
      if (qq < p) { kp = 0; break; }
      bsum += bsv[qq];
    }
    keepf[p] = (unsigned char)kp;
    bsum_s[p] = bsum;
  }
  __syncthreads();
  // sorted-compacted write: rank = #{kept q: js[q] < js[p]} (j distinct kept)
  for (int p = lane; p < cnt; p += 64) {
    if (!keepf[p]) continue;
    int j = js[p];
    int r = 0;
    for (int qq = 0; qq < cnt; ++qq) r += (keepf[qq] && js[qq] < j);
    edgeJB[(size_t)i * CAP + r] =
        (((unsigned)j) << 16) | (unsigned short)f2b(__expf(bsum_s[p]));
  }
  if (lane < 5) {
    int bound = lane * 2048;
    int c = 0;
    for (int qq = 0; qq < cnt; ++qq) c += (keepf[qq] && js[qq] < bound);
    qoff[i * 5 + lane] = c;
  }
}

// ---------------- K5: fused dense flash + sorted-cursor sparse bias (R23) ----
// R21 (global rescan/chunk): +31.7us. R22 (12-reg preload): SPILLED - the
// unified 128-reg budget is full (60 VGPR + 64 AGPR); k5 has <=4 spare regs.
// R23: ONE thread/row (wave 0) walks the row's SORTED edge list with a
// monotone cursor (~5 regs: cursor/end/nextE/denAcc). Each edge is touched
// exactly once per block; per-chunk work = avg 0.5 entries/row. Edge list
// read once, contiguous, L2-hot.
constexpr int TBM = 64;
constexpr int TBN = 128;

template <int NSPLIT>
__global__ __launch_bounds__(512, 4) void k5_flash(
    const short* __restrict__ qk,      // [N][256] bf16
    const short* __restrict__ vt,      // [256][N] bf16
    const unsigned* __restrict__ ejb,  // [N][CAP] sorted packed (j<<16|bf16 eb)
    const int* __restrict__ qoff,      // [N][5] prefix offsets at 2048 bounds
    float* __restrict__ nump,          // [NSPLIT][N][256]
    float* __restrict__ denp) {        // [NSPLIT][N]
  constexpr int QCOLS = NN / NSPLIT;
  constexpr int NCHUNK = QCOLS / TBN;
  constexpr int GPQ = 8 / NSPLIT;
  __shared__ alignas(16) short Qs[TBM * 256];     // 32 KiB, swizzled
  __shared__ alignas(16) short KV[2 * TBN * 64];  // 32 KiB: K dbuf / V subtile
  __shared__ alignas(16) short Ps[TBM * 128];     // 16 KiB, swizzled
  int b = blockIdx.x;
  int q = (b & 7) / GPQ;
  int rb = (b >> 3) * GPQ + (b & (GPQ - 1));
  int tid = threadIdx.x;
  int w = tid >> 6, lane = tid & 63;
  int wr = w >> 2, wc = w & 3;
  int l15 = lane & 15, quad = lane >> 4;
  int rsw = l15 & 7;  // read-side swizzle key (row&7 == l15&7 for all frags)
  int wbase = w * 64; // lane-linear staging base per wave
  int r0 = rb * TBM;
  int cbase = q * QCOLS;

  // ---- stage Q tile once: 4 passes x 8KB, direct to LDS ----
#pragma unroll
  for (int p = 0; p < 4; ++p) {
    int idx = p * 512 + tid;
    int row = idx >> 5, gs = idx & 31;
    gll(qk + (size_t)(r0 + row) * DQK + ((gs ^ (row & 7)) * 8),
        &Qs[(p * 512 + wbase) * 8]);
  }

  // ---- per-row sorted cursor (wave 0: lane == row) ----
  const unsigned* erow = ejb + (size_t)(r0 + (tid & 63)) * CAP;
  int cursor = 0, cend = 0;
  unsigned nextE = 0xFFFFFFFFu;
  if (tid < TBM) {
    int qb = cbase >> 11;  // cbase / 2048
    cursor = qoff[(r0 + tid) * 5 + qb];
    cend = qoff[(r0 + tid) * 5 + qb + (QCOLS >> 11)];
    if (cursor < cend) nextE = erow[cursor];
  }
  float denAcc = 0.f;

  f32x4 o[2][4] = {};
  float den[2] = {0.f, 0.f};
  __syncthreads();

  for (int ch = 0; ch < NCHUNK; ++ch) {
    int c0 = cbase + ch * TBN;
    // ---- stage K slice bk=0 into buf0 ----
#pragma unroll
    for (int p = 0; p < 2; ++p) {
      int idx = p * 512 + tid;
      int col = idx >> 3, gs = idx & 7;
      gll(qk + (size_t)(c0 + col) * DQK + ((gs ^ (col & 7)) * 8),
          &KV[(p * 512 + wbase) * 8]);
    }
    __syncthreads();
    f32x4 s[2][2] = {};  // s[ct][rt] = S^T fragment (swapped operands)
#pragma unroll
    for (int bk = 0; bk < 4; ++bk) {
      int buf = bk & 1;
      if (bk < 3) {
        int nb = buf ^ 1;
#pragma unroll
        for (int p = 0; p < 2; ++p) {
          int idx = p * 512 + tid;
          int col = idx >> 3, gs = idx & 7;
          gll(qk + (size_t)(c0 + col) * DQK + (bk + 1) * 64 + ((gs ^ (col & 7)) * 8),
              &KV[nb * 8192 + (p * 512 + wbase) * 8]);
        }
      }
#pragma unroll
      for (int ks = 0; ks < 2; ++ks) {
        int g = ks * 4 + quad;
        bf16x8 a[2], bb[2];
#pragma unroll
        for (int rt = 0; rt < 2; ++rt)
          a[rt] = *(const bf16x8*)&Qs[(wr * 32 + rt * 16 + l15) * 256 +
                                      ((bk * 8 + g) ^ rsw) * 8];
#pragma unroll
        for (int ct = 0; ct < 2; ++ct)
          bb[ct] = *(const bf16x8*)&KV[buf * 8192 + (wc * 32 + ct * 16 + l15) * 64 +
                                       (g ^ rsw) * 8];
        // swapped: A = K-frag (m = K-col), B = Q-frag (n = Q-row) -> S^T
#pragma unroll
        for (int rt = 0; rt < 2; ++rt)
#pragma unroll
          for (int ct = 0; ct < 2; ++ct)
            s[ct][rt] = __builtin_amdgcn_mfma_f32_16x16x32_bf16(bb[ct], a[rt],
                                                                s[ct][rt], 0, 0, 0);
      }
      __syncthreads();
    }
    // ---- stage V jb=0 early (K dbuf dead); hides V latency under exp ----
#pragma unroll
    for (int p = 0; p < 4; ++p) {
      int idx = p * 512 + tid;
      int feat = idx >> 3, gs = idx & 7;
      gll(vt + (size_t)feat * NN + c0 + ((gs ^ (feat & 7)) * 8),
          &KV[(p * 512 + wbase) * 8]);
    }
    // ---- exp + packed P->LDS (S^T: lane holds 4 consecutive cols/row) ----
#pragma unroll
    for (int rt = 0; rt < 2; ++rt) {
      int row = wr * 32 + rt * 16 + l15;
#pragma unroll
      for (int ct = 0; ct < 2; ++ct) {
        s16x4 pk;
#pragma unroll
        for (int r = 0; r < 4; ++r) {
          float pv = exp2f(s[ct][rt][r] * SCALE_LOG2E);
          den[rt] += pv;
          pk[r] = f2b(pv);
        }
        int cg = wc * 4 + ct * 2 + (quad >> 1);  // col granule = col>>3
        *reinterpret_cast<s16x4*>(
            &Ps[row * 128 + ((cg ^ (row & 7)) * 8 + (quad & 1) * 4)]) = pk;
      }
    }
    __syncthreads();  // drains Ps (lgkm) + V jb=0 (vm)
    // ---- sparse bias: cursor-walk this chunk's sorted entries ----
    if (tid < TBM) {
      unsigned limit = (unsigned)(c0 + TBN);
      while ((nextE >> 16) < limit) {
        unsigned dj = (nextE >> 16) - (unsigned)c0;  // sorted => >= c0
        float eb = b2f((short)(nextE & 0xFFFFu));
        short* ps = &Ps[tid * 128 + (((dj >> 3) ^ (tid & 7)) * 8 + (int)(dj & 7))];
        float oldp = b2f(*ps);
        *ps = f2b(oldp * eb);
        denAcc += oldp * (eb - 1.0f);
        ++cursor;
        nextE = (cursor < cend) ? erow[cursor] : 0xFFFFFFFFu;
      }
    }
    __syncthreads();  // RMW visible before PV pa reads
    // ---- PV: V subtiles of 64 cols ----
#pragma unroll
    for (int jb = 0; jb < 2; ++jb) {
      if (jb == 1) {
        __syncthreads();  // all jb=0 vb reads done before restage
#pragma unroll
        for (int p = 0; p < 4; ++p) {
          int idx = p * 512 + tid;
          int feat = idx >> 3, gs = idx & 7;
          gll(vt + (size_t)feat * NN + c0 + 64 + ((gs ^ (feat & 7)) * 8),
              &KV[(p * 512 + wbase) * 8]);
        }
        __syncthreads();
      }
#pragma unroll
      for (int ks = 0; ks < 2; ++ks) {
        int g = ks * 4 + quad;
        bf16x8 pa[2], vb[4];
#pragma unroll
        for (int rt = 0; rt < 2; ++rt) {
          int row = wr * 32 + rt * 16 + l15;
          pa[rt] = *(const bf16x8*)&Ps[row * 128 +
                                       (((jb * 8 + g) ^ (row & 7)) * 8)];
        }
#pragma unroll
        for (int ft = 0; ft < 4; ++ft)
          vb[ft] = *(const bf16x8*)&KV[(wc * 64 + ft * 16 + l15) * 64 + (g ^ rsw) * 8];
#pragma unroll
        for (int rt = 0; rt < 2; ++rt)
#pragma unroll
          for (int ft = 0; ft < 4; ++ft)
            o[rt][ft] = __builtin_amdgcn_mfma_f32_16x16x32_bf16(pa[rt], vb[ft],
                                                                o[rt][ft], 0, 0, 0);
      }
    }
    __syncthreads();  // protect Ps/KV rewrite next chunk
  }
  // ---- epilogue: write partial num ----
  float* npB = nump + (size_t)q * NN * DQK;
#pragma unroll
  for (int rt = 0; rt < 2; ++rt)
#pragma unroll
    for (int ft = 0; ft < 4; ++ft) {
      int row = r0 + wr * 32 + rt * 16 + quad * 4;
      int feat = wc * 64 + ft * 16 + l15;
#pragma unroll
      for (int r = 0; r < 4; ++r)
        npB[(size_t)(row + r) * DQK + feat] = o[rt][ft][r];
    }
  // ---- den: dense reduce (quads, wc); sparse corr lives in wave-0 lane=row --
  float* dl = reinterpret_cast<float*>(KV);  // [4][TBM], KV dead at epilogue
#pragma unroll
  for (int rt = 0; rt < 2; ++rt) {
    float d = den[rt];
    d += __shfl_xor(d, 16);
    d += __shfl_xor(d, 32);
    if (lane < 16) dl[wc * TBM + wr * 32 + rt * 16 + lane] = d;
  }
  __syncthreads();
  if (tid < TBM) {
    float d = dl[0 * TBM + tid] + dl[1 * TBM + tid] + dl[2 * TBM + tid] +
              dl[3 * TBM + tid] + denAcc;
    denp[q * NN + r0 + tid] = d;
  }
}

// ---------------- K6: pure normalize (bias already folded into k5) -----------
__global__ __launch_bounds__(64) void k6_norm(
    const float* __restrict__ nump, const float* __restrict__ denp,
    float* __restrict__ out, int nsplit) {
  int i = blockIdx.x;
  int lane = threadIdx.x;
  f32x4 a = {0.f, 0.f, 0.f, 0.f};
  float den = 0.f;
  for (int qq = 0; qq < nsplit; ++qq) {
    a += *reinterpret_cast<const f32x4*>(nump + ((size_t)qq * NN + i) * DQK + lane * 4);
    den += denp[qq * NN + i];
  }
  float inv = 1.0f / den;
  a *= inv;
  // feats f = lane*4..+3; f<128 -> new_mag, else new_phase (no 128-crossing)
  float* dst = (lane < 32) ? (out + (size_t)i * DD + lane * 4)
                           : (out + (size_t)NN * DD + (size_t)i * DD + lane * 4 - 128);
  *reinterpret_cast<f32x4*>(dst) = a;
}

// ---------------- workspace layout -------------------------------------------
constexpr size_t OFF_QK = 0;                                   // 4 MiB bf16
constexpr size_t OFF_VT = (size_t)NN * DQK * 2;                // 4 MiB bf16
constexpr size_t OFF_VB16 = OFF_VT + (size_t)DQK * NN * 2;     // 4 MiB bf16
constexpr size_t OFF_BIAS = OFF_VB16 + (size_t)NN * DQK * 2;   // 1 MiB f32
constexpr size_t OFF_CNT = OFF_BIAS + (size_t)EE * 4;
constexpr size_t OFF_SLOT = OFF_CNT + (size_t)NN * 4;
constexpr size_t OFF_EJB = (OFF_SLOT + (size_t)NN * CAP * 4 + 255) & ~(size_t)255;
constexpr size_t OFF_QOFF = OFF_EJB + (size_t)NN * CAP * 4;
constexpr size_t OFF_NUMP = (OFF_QOFF + (size_t)NN * 5 * 4 + 255) & ~(size_t)255;
constexpr size_t WS_NEED4 = OFF_NUMP + 4ull * NN * DQK * 4 + 4ull * NN * 4;
constexpr size_t WS_NEED2 = OFF_NUMP + 2ull * NN * DQK * 4 + 2ull * NN * 4;

extern "C" void kernel_launch(void* const* d_in, const int* in_sizes, int n_in,
                              void* d_out, int out_size, void* d_ws, size_t ws_size,
                              hipStream_t stream) {
  const float* mag = (const float*)d_in[0];
  const float* phase = (const float*)d_in[1];
  const int* eidx = (const int*)d_in[2];
  const float* rbf = (const float*)d_in[3];
  const float* W1 = (const float*)d_in[4];
  const float* b1 = (const float*)d_in[5];
  const float* W2 = (const float*)d_in[6];
  const float* b2 = (const float*)d_in[7];
  float* out = (float*)d_out;
  char* ws = (char*)d_ws;
  if (ws_size < WS_NEED2) return;
  int nsplit = (ws_size >= WS_NEED4) ? 4 : 2;

  short* qkb = (short*)(ws + OFF_QK);
  short* vtb = (short*)(ws + OFF_VT);
  short* vb16 = (short*)(ws + OFF_VB16);
  float* bias = (float*)(ws + OFF_BIAS);
  int* cnt = (int*)(ws + OFF_CNT);
  int* slot = (int*)(ws + OFF_SLOT);
  unsigned* edgeJB = (unsigned*)(ws + OFF_EJB);
  int* qoff = (int*)(ws + OFF_QOFF);
  float* nump = (float*)(ws + OFF_NUMP);
  float* denp = (float*)(ws + OFF_NUMP + (size_t)nsplit * NN * DQK * 4);

  hipMemsetAsync(cnt, 0, (size_t)NN * 4, stream);
  k1_mega<<<5632, 256, 0, stream>>>(mag, phase, qkb, vtb, vb16, rbf, W1, b1, W2,
                                    b2, eidx, bias, cnt, slot);
  k2_merge<<<NN, 64, 0, stream>>>(eidx, bias, cnt, slot, edgeJB, qoff);
  if (nsplit == 4)
    k5_flash<4><<<(NN / TBM) * 4, 512, 0, stream>>>(qkb, vtb, edgeJB, qoff, nump, denp);
  else
    k5_flash<2><<<(NN / TBM) * 2, 512, 0, stream>>>(qkb, vtb, edgeJB, qoff, nump, denp);
  k6_norm<<<NN, 64, 0, stream>>>(nump, denp, out, nsplit);
}